// Round 5
// baseline (278.459 us; speedup 1.0000x reference)
//
#include <hip/hip_runtime.h>
#include <stdint.h>

#define BATCH 8
#define NCH 256
#define BCH 128
#define KFR 32000
#define TOUT 256008
#define KT 32
#define NTPB 8
#define CHUNK (KT * NTPB)        // 256 frames per block
#define NCHUNK (KFR / CHUNK)     // 125

typedef __attribute__((ext_vector_type(8))) short bf16x8;
typedef __attribute__((ext_vector_type(4))) float f32x4;

__device__ __forceinline__ unsigned short f32_to_bf16(float f) {
    unsigned int u = __builtin_bit_cast(unsigned int, f);
    u += 0x7FFFu + ((u >> 16) & 1u);
    return (unsigned short)(u >> 16);
}
__device__ __forceinline__ float bf16_to_f32(unsigned short h) {
    unsigned int u = ((unsigned int)h) << 16;
    return __builtin_bit_cast(float, u);
}
__device__ __forceinline__ unsigned int pack2(float a, float b) {
    return (unsigned int)f32_to_bf16(a) | ((unsigned int)f32_to_bf16(b) << 16);
}

__global__ void convert_weights(const float* __restrict__ Wm,
                                const float* __restrict__ Wb,
                                unsigned short* __restrict__ wbf) {
    int i = blockIdx.x * 256 + threadIdx.x;
    if (i < NCH * BCH) wbf[i] = f32_to_bf16(Wm[i]);
    if (i < 16 * NCH)  wbf[NCH * BCH + i] = f32_to_bf16(Wb[i]);
}

// LDS (units of 4B words):
//   estd [32 f][68 w]  : est^T bf16, XOR-swizzled at 16B granularity
//   xtd  [32 f][132 w] : m/x bf16, XOR-swizzled at 16B granularity
//   locout[2056] f32   : whole-chunk overlap-add accumulator
#define ESTT_W 68
#define XT_W 132
#define ESTT_WORDS (KT * ESTT_W)     // 2176
#define XT_WORDS (KT * XT_W)         // 4224
#define LOC_FLOATS (8 * CHUNK + 8)   // 2056

__global__ __launch_bounds__(256)
__attribute__((amdgpu_waves_per_eu(4, 4)))
void fused_decoder(const float* __restrict__ mix,
                   const float* __restrict__ est,
                   const unsigned short* __restrict__ wbf,
                   float* __restrict__ out) {
    __shared__ __align__(16) unsigned int smem[ESTT_WORDS + XT_WORDS + LOC_FLOATS];
    unsigned int* estd = smem;
    unsigned int* xtd  = smem + ESTT_WORDS;
    unsigned short* estT = reinterpret_cast<unsigned short*>(estd);
    unsigned short* xt   = reinterpret_cast<unsigned short*>(xtd);
    float* locout = reinterpret_cast<float*>(smem + ESTT_WORDS + XT_WORDS);

    const int tid = threadIdx.x;
    const int lane = tid & 63;
    const int wv = tid >> 6;
    const int l15 = lane & 15;
    const int lq = lane >> 4;
    const int f4 = tid & 7;          // staging frame-quad
    const int rbase = tid >> 3;      // staging row base

    const int bid = blockIdx.x;
    const int g = bid / NCHUNK;
    const int c = bid % NCHUNK;

    const float* eg0 = est + ((size_t)g * BCH) * KFR + c * CHUNK;
    const float* mg0 = mix + ((size_t)g * NCH) * KFR + c * CHUNK;

    // zero the chunk accumulator
    for (int s = tid; s < LOC_FLOATS / 4; s += 256) {
        f32x4 z = {0.f, 0.f, 0.f, 0.f};
        *reinterpret_cast<f32x4*>(locout + 4 * s) = z;
    }

    // prologue: issue est[0] loads (named ext_vector regs)
    f32x4 er00, er01, er10, er11;
    {
        int bp0 = rbase, bp1 = 32 + rbase;
        er00 = *reinterpret_cast<const f32x4*>(eg0 + (size_t)(2 * bp0) * KFR + 4 * f4);
        er01 = *reinterpret_cast<const f32x4*>(eg0 + (size_t)(2 * bp0 + 1) * KFR + 4 * f4);
        er10 = *reinterpret_cast<const f32x4*>(eg0 + (size_t)(2 * bp1) * KFR + 4 * f4);
        er11 = *reinterpret_cast<const f32x4*>(eg0 + (size_t)(2 * bp1 + 1) * KFR + 4 * f4);
    }

    for (int t = 0; t < NTPB; ++t) {
        const float* mg = mg0 + t * KT;
        const float* egn = eg0 + (t + 1 < NTPB ? (t + 1) * KT : t * KT);

        // ---- phase A: est regs -> LDS (swizzled); issue est[t+1] + mix[t] ----
        {
            int msk = (f4 >> 1) & 3;
            int base0 = (((rbase >> 2) ^ msk) << 2) + (rbase & 3);
            int base1 = ((((32 + rbase) >> 2) ^ msk) << 2) + ((32 + rbase) & 3);
#pragma unroll
            for (int i = 0; i < 4; ++i) {
                estd[(4 * f4 + i) * ESTT_W + base0] = pack2(er00[i], er01[i]);
                estd[(4 * f4 + i) * ESTT_W + base1] = pack2(er10[i], er11[i]);
            }
        }
        {
            int bp0 = rbase, bp1 = 32 + rbase;
            er00 = *reinterpret_cast<const f32x4*>(egn + (size_t)(2 * bp0) * KFR + 4 * f4);
            er01 = *reinterpret_cast<const f32x4*>(egn + (size_t)(2 * bp0 + 1) * KFR + 4 * f4);
            er10 = *reinterpret_cast<const f32x4*>(egn + (size_t)(2 * bp1) * KFR + 4 * f4);
            er11 = *reinterpret_cast<const f32x4*>(egn + (size_t)(2 * bp1 + 1) * KFR + 4 * f4);
        }
        // this tile's mix, in flight until phase C (8 named ext_vector regs)
        f32x4 mr0a, mr0b, mr1a, mr1b, mr2a, mr2b, mr3a, mr3b;
        {
            mr0a = *reinterpret_cast<const f32x4*>(mg + (size_t)(2 * (0 * 32 + rbase)) * KFR + 4 * f4);
            mr0b = *reinterpret_cast<const f32x4*>(mg + (size_t)(2 * (0 * 32 + rbase) + 1) * KFR + 4 * f4);
            mr1a = *reinterpret_cast<const f32x4*>(mg + (size_t)(2 * (1 * 32 + rbase)) * KFR + 4 * f4);
            mr1b = *reinterpret_cast<const f32x4*>(mg + (size_t)(2 * (1 * 32 + rbase) + 1) * KFR + 4 * f4);
            mr2a = *reinterpret_cast<const f32x4*>(mg + (size_t)(2 * (2 * 32 + rbase)) * KFR + 4 * f4);
            mr2b = *reinterpret_cast<const f32x4*>(mg + (size_t)(2 * (2 * 32 + rbase) + 1) * KFR + 4 * f4);
            mr3a = *reinterpret_cast<const f32x4*>(mg + (size_t)(2 * (3 * 32 + rbase)) * KFR + 4 * f4);
            mr3b = *reinterpret_cast<const f32x4*>(mg + (size_t)(2 * (3 * 32 + rbase) + 1) * KFR + 4 * f4);
        }
        __syncthreads();

        // ---- phase B: GEMM1 m[n][f] = W[n][b] est[b][f]; epilogue interleaved
        //      per nt so only 8 acc regs are live at a time ----
#pragma unroll
        for (int nt = 0; nt < 4; ++nt) {
            int n = 64 * wv + 16 * nt + l15;
            bf16x8 wf0 = *reinterpret_cast<const bf16x8*>(wbf + n * BCH + 0 + 8 * lq);
            bf16x8 wf1 = *reinterpret_cast<const bf16x8*>(wbf + n * BCH + 32 + 8 * lq);
            bf16x8 wf2 = *reinterpret_cast<const bf16x8*>(wbf + n * BCH + 64 + 8 * lq);
            bf16x8 wf3 = *reinterpret_cast<const bf16x8*>(wbf + n * BCH + 96 + 8 * lq);
            f32x4 a0 = {0.f, 0.f, 0.f, 0.f};
            f32x4 a1 = {0.f, 0.f, 0.f, 0.f};
            {
                int f = l15;
                int msk = (l15 >> 3) & 3;
                bf16x8 b0 = *reinterpret_cast<const bf16x8*>(estT + f * (2 * ESTT_W) + 8 * ((0 + lq) ^ msk));
                bf16x8 b1 = *reinterpret_cast<const bf16x8*>(estT + f * (2 * ESTT_W) + 8 * ((4 + lq) ^ msk));
                bf16x8 b2 = *reinterpret_cast<const bf16x8*>(estT + f * (2 * ESTT_W) + 8 * ((8 + lq) ^ msk));
                bf16x8 b3 = *reinterpret_cast<const bf16x8*>(estT + f * (2 * ESTT_W) + 8 * ((12 + lq) ^ msk));
                a0 = __builtin_amdgcn_mfma_f32_16x16x32_bf16(wf0, b0, a0, 0, 0, 0);
                a0 = __builtin_amdgcn_mfma_f32_16x16x32_bf16(wf1, b1, a0, 0, 0, 0);
                a0 = __builtin_amdgcn_mfma_f32_16x16x32_bf16(wf2, b2, a0, 0, 0, 0);
                a0 = __builtin_amdgcn_mfma_f32_16x16x32_bf16(wf3, b3, a0, 0, 0, 0);
            }
            {
                int f = 16 + l15;
                int msk = (2 + (l15 >> 3)) & 3;
                bf16x8 b0 = *reinterpret_cast<const bf16x8*>(estT + f * (2 * ESTT_W) + 8 * ((0 + lq) ^ msk));
                bf16x8 b1 = *reinterpret_cast<const bf16x8*>(estT + f * (2 * ESTT_W) + 8 * ((4 + lq) ^ msk));
                bf16x8 b2 = *reinterpret_cast<const bf16x8*>(estT + f * (2 * ESTT_W) + 8 * ((8 + lq) ^ msk));
                bf16x8 b3 = *reinterpret_cast<const bf16x8*>(estT + f * (2 * ESTT_W) + 8 * ((12 + lq) ^ msk));
                a1 = __builtin_amdgcn_mfma_f32_16x16x32_bf16(wf0, b0, a1, 0, 0, 0);
                a1 = __builtin_amdgcn_mfma_f32_16x16x32_bf16(wf1, b1, a1, 0, 0, 0);
                a1 = __builtin_amdgcn_mfma_f32_16x16x32_bf16(wf2, b2, a1, 0, 0, 0);
                a1 = __builtin_amdgcn_mfma_f32_16x16x32_bf16(wf3, b3, a1, 0, 0, 0);
            }
            // epilogue for this nt: m -> xt (bf16, swizzled)
            {
                int v = 8 * wv + 2 * nt + (lq >> 1);
                int f0 = l15;
                int msk0 = (l15 >> 3) & 3;
                int w0 = f0 * XT_W + ((v ^ msk0) << 2) + 2 * (lq & 1);
                uint2 u0;
                u0.x = pack2(a0[0], a0[1]);
                u0.y = pack2(a0[2], a0[3]);
                *reinterpret_cast<uint2*>(xtd + w0) = u0;
                int f1 = 16 + l15;
                int msk1 = (2 + (l15 >> 3)) & 3;
                int w1 = f1 * XT_W + ((v ^ msk1) << 2) + 2 * (lq & 1);
                uint2 u1;
                u1.x = pack2(a1[0], a1[1]);
                u1.y = pack2(a1[2], a1[3]);
                *reinterpret_cast<uint2*>(xtd + w1) = u1;
            }
        }
        __syncthreads();

        // ---- phase C: x = mix * relu(m), in-place on xt (swizzled b32 RMW) ----
        {
            int msk = (f4 >> 1) & 3;
#pragma unroll
            for (int it = 0; it < 4; ++it) {
                int np = it * 32 + rbase;
                int base = (((np >> 2) ^ msk) << 2) + (np & 3);
                f32x4 va = (it == 0) ? mr0a : (it == 1) ? mr1a : (it == 2) ? mr2a : mr3a;
                f32x4 vb = (it == 0) ? mr0b : (it == 1) ? mr1b : (it == 2) ? mr2b : mr3b;
#pragma unroll
                for (int i = 0; i < 4; ++i) {
                    int idx = (4 * f4 + i) * XT_W + base;
                    unsigned int p = xtd[idx];
                    float m0 = bf16_to_f32((unsigned short)(p & 0xFFFFu));
                    float m1 = bf16_to_f32((unsigned short)(p >> 16));
                    float x0 = (m0 > 0.f) ? va[i] * m0 : 0.f;
                    float x1 = (m1 > 0.f) ? vb[i] * m1 : 0.f;
                    xtd[idx] = pack2(x0, x1);
                }
            }
        }
        __syncthreads();

        // ---- phase D: GEMM2 y[l][f] = Wb[l][n] x[n][f]; overlap-add into locout ----
        f32x4 acc2 = {0.f, 0.f, 0.f, 0.f};
        if (wv < 2) {
            int f = 16 * wv + l15;
            int msk = (2 * wv + (l15 >> 3)) & 3;
#pragma unroll
            for (int ks = 0; ks < 8; ++ks) {
                bf16x8 a = *reinterpret_cast<const bf16x8*>(
                    wbf + NCH * BCH + l15 * NCH + 32 * ks + 8 * lq);
                bf16x8 b = *reinterpret_cast<const bf16x8*>(
                    xt + f * (2 * XT_W) + 8 * ((4 * ks + lq) ^ msk));
                acc2 = __builtin_amdgcn_mfma_f32_16x16x32_bf16(a, b, acc2, 0, 0, 0);
            }
        }
        if (wv < 2 && lq < 2) {          // pass 1: louts 0..7, disjoint addresses
            int f = 16 * wv + l15;
            int base = 256 * t + 8 * f + 4 * lq;
#pragma unroll
            for (int r = 0; r < 4; ++r) locout[base + r] += acc2[r];
        }
        __syncthreads();
        if (wv < 2 && lq >= 2) {         // pass 2: louts 8..15, disjoint addresses
            int f = 16 * wv + l15;
            int base = 256 * t + 8 * f + 4 * lq;
#pragma unroll
            for (int r = 0; r < 4; ++r) locout[base + r] += acc2[r];
        }
        // next conflicting LDS access is after phase-A barrier
    }
    __syncthreads();

    // ---- final store: whole chunk, plain float4 interior, atomic 8-float edges ----
    {
        float* og = out + (size_t)g * TOUT + (size_t)(8 * CHUNK) * c;
        for (int s = tid; s < LOC_FLOATS / 4; s += 256) {
            f32x4 v = *reinterpret_cast<const f32x4*>(locout + 4 * s);
            if (s >= 2 && s < (LOC_FLOATS / 4 - 2)) {
                *reinterpret_cast<f32x4*>(og + 4 * s) = v;
            } else {
#pragma unroll
                for (int r = 0; r < 4; ++r) atomicAdd(og + 4 * s + r, v[r]);
            }
        }
    }
}

extern "C" void kernel_launch(void* const* d_in, const int* in_sizes, int n_in,
                              void* d_out, int out_size, void* d_ws, size_t ws_size,
                              hipStream_t stream) {
    const float* mix = (const float*)d_in[0];   // [8][256][32000]
    const float* est = (const float*)d_in[1];   // [8][128][32000]
    const float* Wm  = (const float*)d_in[2];   // [256][128]
    const float* Wb  = (const float*)d_in[3];   // [16][256]
    unsigned short* wbf = (unsigned short*)d_ws;

    hipMemsetAsync(d_out, 0, (size_t)out_size * sizeof(float), stream);
    convert_weights<<<128, 256, 0, stream>>>(Wm, Wb, wbf);
    fused_decoder<<<BATCH * NCHUNK, 256, 0, stream>>>(mix, est, wbf, (float*)d_out);
}

// Round 6
// 140.521 us; speedup vs baseline: 1.9816x; 1.9816x over previous
//
#include <hip/hip_runtime.h>
#include <stdint.h>

#define BATCH 8
#define NCH 256
#define BCH 128
#define KFR 32000
#define TOUT 256008
#define KT 32
#define NTPB 8
#define CHUNK (KT * NTPB)        // 256 frames per block
#define NCHUNK (KFR / CHUNK)     // 125

typedef __attribute__((ext_vector_type(8))) short bf16x8;
typedef __attribute__((ext_vector_type(4))) float f32x4;

__device__ __forceinline__ unsigned short f32_to_bf16(float f) {
    unsigned int u = __builtin_bit_cast(unsigned int, f);
    u += 0x7FFFu + ((u >> 16) & 1u);
    return (unsigned short)(u >> 16);
}
__device__ __forceinline__ unsigned int pack2(float a, float b) {
    return (unsigned int)f32_to_bf16(a) | ((unsigned int)f32_to_bf16(b) << 16);
}
// 4 strided scalar loads (stride = KFR rows) into an ext_vector (SROA-safe)
__device__ __forceinline__ f32x4 mload(const float* p) {
    f32x4 v;
    v[0] = p[0];
    v[1] = p[(size_t)KFR];
    v[2] = p[(size_t)2 * KFR];
    v[3] = p[(size_t)3 * KFR];
    return v;
}

__global__ void convert_weights(const float* __restrict__ Wm,
                                const float* __restrict__ Wb,
                                unsigned short* __restrict__ wbf) {
    int i = blockIdx.x * 256 + threadIdx.x;
    if (i < NCH * BCH) wbf[i] = f32_to_bf16(Wm[i]);
    if (i < 16 * NCH)  wbf[NCH * BCH + i] = f32_to_bf16(Wb[i]);
}

// LDS (units of 4B words):
//   estd [32 f][68 w]  : est^T bf16, XOR-swizzled at 16B granularity
//   xtd  [32 f][132 w] : x bf16, XOR-swizzled at 16B granularity
//   locout[2056] f32   : whole-chunk overlap-add accumulator
#define ESTT_W 68
#define XT_W 132
#define ESTT_WORDS (KT * ESTT_W)     // 2176
#define XT_WORDS (KT * XT_W)         // 4224
#define LOC_FLOATS (8 * CHUNK + 8)   // 2056

// one GEMM1 16x16 tile (nt,ft) + fused relu*mix epilogue -> xt
#define G1(NT, FT, MM) { \
    const unsigned short* wr = wbf + (64 * wv + 16 * (NT) + l15) * BCH + 8 * lq; \
    bf16x8 w0 = *reinterpret_cast<const bf16x8*>(wr); \
    bf16x8 w1 = *reinterpret_cast<const bf16x8*>(wr + 32); \
    bf16x8 w2 = *reinterpret_cast<const bf16x8*>(wr + 64); \
    bf16x8 w3 = *reinterpret_cast<const bf16x8*>(wr + 96); \
    int f = 16 * (FT) + l15; \
    int msk = (2 * (FT) + (l15 >> 3)) & 3; \
    const unsigned short* br = estT + f * (2 * ESTT_W); \
    f32x4 a = {0.f, 0.f, 0.f, 0.f}; \
    a = __builtin_amdgcn_mfma_f32_16x16x32_bf16(w0, *reinterpret_cast<const bf16x8*>(br + 8 * ((0  + lq) ^ msk)), a, 0, 0, 0); \
    a = __builtin_amdgcn_mfma_f32_16x16x32_bf16(w1, *reinterpret_cast<const bf16x8*>(br + 8 * ((4  + lq) ^ msk)), a, 0, 0, 0); \
    a = __builtin_amdgcn_mfma_f32_16x16x32_bf16(w2, *reinterpret_cast<const bf16x8*>(br + 8 * ((8  + lq) ^ msk)), a, 0, 0, 0); \
    a = __builtin_amdgcn_mfma_f32_16x16x32_bf16(w3, *reinterpret_cast<const bf16x8*>(br + 8 * ((12 + lq) ^ msk)), a, 0, 0, 0); \
    float x0 = (a[0] > 0.f) ? (MM)[0] * a[0] : 0.f; \
    float x1 = (a[1] > 0.f) ? (MM)[1] * a[1] : 0.f; \
    float x2 = (a[2] > 0.f) ? (MM)[2] * a[2] : 0.f; \
    float x3 = (a[3] > 0.f) ? (MM)[3] * a[3] : 0.f; \
    int v = 8 * wv + 2 * (NT) + (lq >> 1); \
    uint2 uu; uu.x = pack2(x0, x1); uu.y = pack2(x2, x3); \
    *reinterpret_cast<uint2*>(xtd + f * XT_W + ((v ^ msk) << 2) + 2 * (lq & 1)) = uu; \
}

__global__ __launch_bounds__(256, 4)
void fused_decoder(const float* __restrict__ mix,
                   const float* __restrict__ est,
                   const unsigned short* __restrict__ wbf,
                   float* __restrict__ out) {
    __shared__ __align__(16) unsigned int smem[ESTT_WORDS + XT_WORDS + LOC_FLOATS];
    unsigned int* estd = smem;
    unsigned int* xtd  = smem + ESTT_WORDS;
    unsigned short* estT = reinterpret_cast<unsigned short*>(estd);
    unsigned short* xt   = reinterpret_cast<unsigned short*>(xtd);
    float* locout = reinterpret_cast<float*>(smem + ESTT_WORDS + XT_WORDS);

    const int tid = threadIdx.x;
    const int lane = tid & 63;
    const int wv = tid >> 6;
    const int l15 = lane & 15;
    const int lq = lane >> 4;
    const int f4 = tid & 7;          // staging frame-quad
    const int rbase = tid >> 3;      // staging row base

    const int bid = blockIdx.x;
    const int g = bid / NCHUNK;
    const int c = bid % NCHUNK;

    const float* eg0 = est + ((size_t)g * BCH) * KFR + c * CHUNK;
    const float* mg0 = mix + ((size_t)g * NCH) * KFR + c * CHUNK;

    // zero the chunk accumulator
    for (int s = tid; s < LOC_FLOATS / 4; s += 256) {
        f32x4 z = {0.f, 0.f, 0.f, 0.f};
        *reinterpret_cast<f32x4*>(locout + 4 * s) = z;
    }

    // prologue: est[0] loads (16 regs; 128B-contiguous per 8 lanes)
    f32x4 er00, er01, er10, er11;
    {
        int bp0 = rbase, bp1 = 32 + rbase;
        er00 = *reinterpret_cast<const f32x4*>(eg0 + (size_t)(2 * bp0) * KFR + 4 * f4);
        er01 = *reinterpret_cast<const f32x4*>(eg0 + (size_t)(2 * bp0 + 1) * KFR + 4 * f4);
        er10 = *reinterpret_cast<const f32x4*>(eg0 + (size_t)(2 * bp1) * KFR + 4 * f4);
        er11 = *reinterpret_cast<const f32x4*>(eg0 + (size_t)(2 * bp1 + 1) * KFR + 4 * f4);
    }

    for (int t = 0; t < NTPB; ++t) {
        const float* mg = mg0 + t * KT;

        // ---- phase A: est regs -> LDS (swizzled) ----
        {
            int msk = (f4 >> 1) & 3;
            int base0 = (((rbase >> 2) ^ msk) << 2) + (rbase & 3);
            int base1 = ((((32 + rbase) >> 2) ^ msk) << 2) + ((32 + rbase) & 3);
#pragma unroll
            for (int i = 0; i < 4; ++i) {
                estd[(4 * f4 + i) * ESTT_W + base0] = pack2(er00[i], er01[i]);
                estd[(4 * f4 + i) * ESTT_W + base1] = pack2(er10[i], er11[i]);
            }
        }
        __syncthreads();   // estT ready

        // ---- phase B: GEMM1 + fused relu*mix epilogue -> xt ----
        // ft-pass 0: issue its 16 mix dwords up front, consume per nt
        const float* pm = mg + (size_t)(64 * wv + 4 * lq) * KFR + l15;
        f32x4 ma0 = mload(pm);
        f32x4 ma1 = mload(pm + (size_t)16 * KFR);
        f32x4 ma2 = mload(pm + (size_t)32 * KFR);
        f32x4 ma3 = mload(pm + (size_t)48 * KFR);
        G1(0, 0, ma0)
        G1(1, 0, ma1)
        // issue ft-pass-1 mix loads mid-pass (hidden behind remaining MFMAs)
        f32x4 mb0 = mload(pm + 16);
        f32x4 mb1 = mload(pm + (size_t)16 * KFR + 16);
        f32x4 mb2 = mload(pm + (size_t)32 * KFR + 16);
        f32x4 mb3 = mload(pm + (size_t)48 * KFR + 16);
        G1(2, 0, ma2)
        G1(3, 0, ma3)
        G1(0, 1, mb0)
        G1(1, 1, mb1)
        G1(2, 1, mb2)
        G1(3, 1, mb3)
        __syncthreads();   // xt ready

        // ---- phase D: issue est[t+1]; GEMM2; overlap-add into locout ----
        {
            const float* egn = eg0 + (t + 1 < NTPB ? (t + 1) * KT : t * KT);
            int bp0 = rbase, bp1 = 32 + rbase;
            er00 = *reinterpret_cast<const f32x4*>(egn + (size_t)(2 * bp0) * KFR + 4 * f4);
            er01 = *reinterpret_cast<const f32x4*>(egn + (size_t)(2 * bp0 + 1) * KFR + 4 * f4);
            er10 = *reinterpret_cast<const f32x4*>(egn + (size_t)(2 * bp1) * KFR + 4 * f4);
            er11 = *reinterpret_cast<const f32x4*>(egn + (size_t)(2 * bp1 + 1) * KFR + 4 * f4);
        }
        f32x4 acc2 = {0.f, 0.f, 0.f, 0.f};
        if (wv < 2) {
            int f = 16 * wv + l15;
            int msk = (2 * wv + (l15 >> 3)) & 3;
#pragma unroll
            for (int ks = 0; ks < 8; ++ks) {
                bf16x8 a = *reinterpret_cast<const bf16x8*>(
                    wbf + NCH * BCH + l15 * NCH + 32 * ks + 8 * lq);
                bf16x8 b = *reinterpret_cast<const bf16x8*>(
                    xt + f * (2 * XT_W) + 8 * ((4 * ks + lq) ^ msk));
                acc2 = __builtin_amdgcn_mfma_f32_16x16x32_bf16(a, b, acc2, 0, 0, 0);
            }
        }
        if (wv < 2 && lq < 2) {          // pass 1: louts 0..7
            int f = 16 * wv + l15;
            int base = 256 * t + 8 * f + 4 * lq;
#pragma unroll
            for (int r = 0; r < 4; ++r) locout[base + r] += acc2[r];
        }
        __syncthreads();
        if (wv < 2 && lq >= 2) {         // pass 2: louts 8..15
            int f = 16 * wv + l15;
            int base = 256 * t + 8 * f + 4 * lq;
#pragma unroll
            for (int r = 0; r < 4; ++r) locout[base + r] += acc2[r];
        }
        // pass2 writes locout only; phase A(t+1) writes estd (disjoint) -> no barrier
    }
    __syncthreads();

    // ---- final store: whole chunk, plain float4 interior, atomic 8-float edges ----
    {
        float* og = out + (size_t)g * TOUT + (size_t)(8 * CHUNK) * c;
        for (int s = tid; s < LOC_FLOATS / 4; s += 256) {
            f32x4 v = *reinterpret_cast<const f32x4*>(locout + 4 * s);
            if (s >= 2 && s < (LOC_FLOATS / 4 - 2)) {
                *reinterpret_cast<f32x4*>(og + 4 * s) = v;
            } else {
#pragma unroll
                for (int r = 0; r < 4; ++r) atomicAdd(og + 4 * s + r, v[r]);
            }
        }
    }
}

extern "C" void kernel_launch(void* const* d_in, const int* in_sizes, int n_in,
                              void* d_out, int out_size, void* d_ws, size_t ws_size,
                              hipStream_t stream) {
    const float* mix = (const float*)d_in[0];   // [8][256][32000]
    const float* est = (const float*)d_in[1];   // [8][128][32000]
    const float* Wm  = (const float*)d_in[2];   // [256][128]
    const float* Wb  = (const float*)d_in[3];   // [16][256]
    unsigned short* wbf = (unsigned short*)d_ws;

    hipMemsetAsync(d_out, 0, (size_t)out_size * sizeof(float), stream);
    convert_weights<<<128, 256, 0, stream>>>(Wm, Wb, wbf);
    fused_decoder<<<BATCH * NCHUNK, 256, 0, stream>>>(mix, est, wbf, (float*)d_out);
}